// Round 1
// 598.058 us; speedup vs baseline: 1.0396x; 1.0396x over previous
//
#include <hip/hip_runtime.h>

// ---------- types ----------
typedef int      i32x4 __attribute__((ext_vector_type(4)));
typedef _Float16 f16x2 __attribute__((ext_vector_type(2)));

// ---------- helpers ----------
__device__ __forceinline__ void async_cp16(const void* g, void* l) {
    __builtin_amdgcn_global_load_lds(
        (const __attribute__((address_space(1))) void*)g,
        (__attribute__((address_space(3))) void*)l, 16, 0, 0);
}

// stage one 256x64B operand K-half unit: 2 x global_load_lds (g0 rows 0-127, g1 rows 128-255)
__device__ __forceinline__ void stage2(const signed char* base, long long o0,
                                       long long o1, signed char* slab, int ldst) {
    async_cp16(base + o0, slab + ldst);
    async_cp16(base + o1, slab + 8192 + ldst);
}

// 4 A-fragments (one M-half) from a K-half slab. rowb = wm*8192 + lm*64 + coff.
__device__ __forceinline__ void rd_a4(const signed char* slab, int mh, int rowb, i32x4* af) {
#pragma unroll
    for (int i = 0; i < 4; ++i)
        af[i] = *(const i32x4*)(slab + mh * 4096 + i * 1024 + rowb);
}
// 4 B-fragments from a K-half slab. rowb = wn*4096 + lm*64 + coff.
__device__ __forceinline__ void rd_b4(const signed char* slab, int rowb, i32x4* bf) {
#pragma unroll
    for (int j = 0; j < 4; ++j)
        bf[j] = *(const i32x4*)(slab + j * 1024 + rowb);
}
__device__ __forceinline__ void mfma16(const i32x4* af, const i32x4* bf,
                                       i32x4 acc[8][4], int mh) {
#pragma unroll
    for (int i = 0; i < 4; ++i)
#pragma unroll
        for (int j = 0; j < 4; ++j)
            acc[mh * 4 + i][j] = __builtin_amdgcn_mfma_i32_16x16x64_i8(
                af[i], bf[j], acc[mh * 4 + i][j], 0, 0, 0);
}

#define BAR  __builtin_amdgcn_s_barrier()
#define LGKM0 do { asm volatile("s_waitcnt lgkmcnt(0)" ::: "memory"); \
                   __builtin_amdgcn_sched_barrier(0); } while (0)
#define VMW(N) do { asm volatile("s_waitcnt vmcnt(" #N ")" ::: "memory"); \
                    __builtin_amdgcn_sched_barrier(0); } while (0)
#define VMW_NONE do { } while (0)

// ---------- 8-phase 256^2 int8 GEMM ----------
// C[M,N] = sum_k A[M,K]*B[N,K] (int8 codes, i32 MFMA), BM=BN=256, BK=128 bytes.
// LDS: ring of 4 K-half slabs (256 rows x 64 B) per operand = 128 KiB.
// Slab swizzle: chunk c (16B) of row r stored at slot c ^ ((r>>1)&3) -> frag
// ds_read_b128 is 2-way bank aliased = free; staging pre-swizzles the GLOBAL
// source (global_load_lds dst must be linear: wave-uniform base + lane*16).
// Ledger (per wave, 4 load-instr per unit u; src k-offset = u*64):
//   prologue: units 0,1,2 (12 instr) ; tile t phases issue u=2t+3 (ph0:A,ph1:B)
//   and u=2t+4 (ph2:A, ph3:B). Gates: vmcnt(8) before closing barriers of ph1
//   (needs unit 2t+1; newer = 2t+2,2t+3 = 8 instr) and ph3 (needs 2t+2; newer
//   = 2t+3,2t+4 = 8). Peeled tail: (8,4) then (0,none). Barrier after each gate
//   makes the guarantee cross-wave. Slab overwrite safety: unit u+4's issue is
//   always after the barrier closing the last phase that read unit u.
template <bool GELU, typename OutT>
__global__ __launch_bounds__(512, 2) void gemm_i8_8ph(
    const signed char* __restrict__ A,   // M x K int8 codes
    const signed char* __restrict__ B,   // N x K int8 ternary
    const float* __restrict__ rowinv,    // per-row dequant (absmax/127)
    const float* __restrict__ wscale,    // &scale_w
    const float* __restrict__ bias,      // N
    OutT* __restrict__ C,                // M x N
    int M, int N, int K)
{
    __shared__ signed char sA[4][16384];
    __shared__ signed char sB[4][16384];

    const int tid  = threadIdx.x;
    const int lane = tid & 63;
    const int wid  = tid >> 6;       // 0..7
    const int lm   = lane & 15;
    const int quad = lane >> 4;
    const int wm   = wid >> 2;       // 0..1  (M half)
    const int wn   = wid & 3;        // 0..3  (N quarter)

    // T1: bijective XCD swizzle (nwg % 8 == 0 for both launches)
    const int nwg = gridDim.x * gridDim.y;
    const int bid = blockIdx.y * gridDim.x + blockIdx.x;
    const int cpx = nwg >> 3;
    const int wg  = (bid & 7) * cpx + (bid >> 3);
    const int bx  = wg % gridDim.x;
    const int by  = wg / gridDim.x;

    const long long rowA0 = (long long)by * 256;
    const long long rowB0 = (long long)bx * 256;

    // staging: thread t -> slab row (t>>2)+128g, slot t&3; source chunk pre-swizzled
    const int srow   = tid >> 2;                       // 0..127
    const int schunk = (tid & 3) ^ ((tid >> 3) & 3);   // slot ^ ((row>>1)&3)
    const long long offA0 = (rowA0 + srow) * (long long)K + schunk * 16;
    const long long offA1 = offA0 + 128LL * K;
    const long long offB0 = (rowB0 + srow) * (long long)K + schunk * 16;
    const long long offB1 = offB0 + 128LL * K;
    const int ldst = tid * 16;

    // fragment read bases: slot = quad ^ ((lm>>1)&3) (row&6>>1 == lm>>1 & 3)
    const int coff  = (quad ^ ((lm >> 1) & 3)) << 4;
    const int rowbA = wm * 8192 + lm * 64 + coff;
    const int rowbB = wn * 4096 + lm * 64 + coff;

    const signed char* Ab = A;
    const signed char* Bb = B;
    const int NTt = K >> 7;          // 128-byte K-tiles (16 or 64 here)

    i32x4 acc[8][4] = {};

#define TILE_BODY(T, DOA, DOB, VMA, VMB) do {                                   \
        const int u0_ = 2 * (T);                                                \
        const signed char* sa0_ = sA[u0_ & 3];                                  \
        const signed char* sb0_ = sB[u0_ & 3];                                  \
        const signed char* sa1_ = sA[(u0_ + 1) & 3];                            \
        const signed char* sb1_ = sB[(u0_ + 1) & 3];                            \
        i32x4 af[4], bf[4];                                                     \
        /* phase 0: ks=0 mh=0 */                                                \
        rd_a4(sa0_, 0, rowbA, af);                                              \
        rd_b4(sb0_, rowbB, bf);                                                 \
        if (DOA) stage2(Ab + (long long)(u0_ + 3) * 64, offA0, offA1,           \
                        sA[(u0_ + 3) & 3], ldst);                               \
        BAR; LGKM0;                                                             \
        __builtin_amdgcn_s_setprio(1); mfma16(af, bf, acc, 0);                  \
        __builtin_amdgcn_s_setprio(0);                                          \
        BAR;                                                                    \
        /* phase 1: ks=0 mh=1 (reuse bf) */                                     \
        rd_a4(sa0_, 1, rowbA, af);                                              \
        if (DOA) stage2(Bb + (long long)(u0_ + 3) * 64, offB0, offB1,           \
                        sB[(u0_ + 3) & 3], ldst);                               \
        BAR; LGKM0;                                                             \
        __builtin_amdgcn_s_setprio(1); mfma16(af, bf, acc, 1);                  \
        __builtin_amdgcn_s_setprio(0);                                          \
        VMA; BAR;                                                               \
        /* phase 2: ks=1 mh=0 */                                                \
        rd_a4(sa1_, 0, rowbA, af);                                              \
        rd_b4(sb1_, rowbB, bf);                                                 \
        if (DOB) stage2(Ab + (long long)(u0_ + 4) * 64, offA0, offA1,           \
                        sA[(u0_ + 4) & 3], ldst);                               \
        BAR; LGKM0;                                                             \
        __builtin_amdgcn_s_setprio(1); mfma16(af, bf, acc, 0);                  \
        __builtin_amdgcn_s_setprio(0);                                          \
        BAR;                                                                    \
        /* phase 3: ks=1 mh=1 (reuse bf) */                                     \
        rd_a4(sa1_, 1, rowbA, af);                                              \
        if (DOB) stage2(Bb + (long long)(u0_ + 4) * 64, offB0, offB1,           \
                        sB[(u0_ + 4) & 3], ldst);                               \
        BAR; LGKM0;                                                             \
        __builtin_amdgcn_s_setprio(1); mfma16(af, bf, acc, 1);                  \
        __builtin_amdgcn_s_setprio(0);                                          \
        VMB; BAR;                                                               \
    } while (0)

    // prologue: units 0,1,2 (order per unit: A g0, A g1, B g0, B g1)
#pragma unroll
    for (int u = 0; u < 3; ++u) {
        stage2(Ab + (long long)u * 64, offA0, offA1, sA[u], ldst);
        stage2(Bb + (long long)u * 64, offB0, offB1, sB[u], ldst);
    }
    VMW(8); BAR;   // unit 0 landed everywhere

    for (int t = 0; t < NTt - 2; ++t)
        TILE_BODY(t, true, true, VMW(8), VMW(8));
    TILE_BODY(NTt - 2, true, false, VMW(8), VMW(4));
    TILE_BODY(NTt - 1, false, false, VMW(0), VMW_NONE);
#undef TILE_BODY

    // epilogue. C/D layout (m89/m91, dtype-independent): col=lane&15, row=quad*4+reg
    const float sw = wscale[0];
    float bj[4];
#pragma unroll
    for (int j = 0; j < 4; ++j)
        bj[j] = bias[rowB0 + wn * 64 + j * 16 + lm];
#pragma unroll
    for (int mi = 0; mi < 8; ++mi) {
#pragma unroll
        for (int r = 0; r < 4; ++r) {
            const long long gr = rowA0 + wm * 128 + mi * 16 + quad * 4 + r;
            const float rs = sw * rowinv[gr];
#pragma unroll
            for (int j = 0; j < 4; ++j) {
                const long long gc = rowB0 + wn * 64 + j * 16 + lm;
                float v = (float)acc[mi][j][r] * rs + bj[j];
                if constexpr (GELU)
                    v = 0.5f * v * (1.0f + erff(v * 0.70710678118654752f));
                C[gr * (long long)N + gc] = (OutT)v;
            }
        }
    }
}

// ---------- LN + absmax int8 fake-quant over x (d=2048, fp32 in, int8 out) ----------
// Column-order-preserving stores: thread t holds cols {4t..4t+3} and
// {1024+4t..1024+4t+3}; they MUST land at those byte offsets.
__global__ __launch_bounds__(256) void ln_quant_x(
    const float* __restrict__ x, signed char* __restrict__ xq,
    float* __restrict__ xinv)
{
    const int t = blockIdx.x;
    const int tid = threadIdx.x;
    const int lane = tid & 63, wid = tid >> 6;
    const float4* row = (const float4*)(x + (long long)t * 2048);
    float4 v0 = row[tid];
    float4 v1 = row[tid + 256];
    float vv[8] = {v0.x, v0.y, v0.z, v0.w, v1.x, v1.y, v1.z, v1.w};

    float s = 0.f, mn = vv[0], mx = vv[0];
#pragma unroll
    for (int i = 0; i < 8; ++i) { s += vv[i]; mn = fminf(mn, vv[i]); mx = fmaxf(mx, vv[i]); }
#pragma unroll
    for (int off = 32; off > 0; off >>= 1) {
        s += __shfl_down(s, off);
        mn = fminf(mn, __shfl_down(mn, off));
        mx = fmaxf(mx, __shfl_down(mx, off));
    }
    __shared__ float rS[4], rMn[4], rMx[4];
    if (lane == 0) { rS[wid] = s; rMn[wid] = mn; rMx[wid] = mx; }
    __syncthreads();
    s  = rS[0] + rS[1] + rS[2] + rS[3];
    mn = fminf(fminf(rMn[0], rMn[1]), fminf(rMn[2], rMn[3]));
    mx = fmaxf(fmaxf(rMx[0], rMx[1]), fmaxf(rMx[2], rMx[3]));
    const float mu = s * (1.0f / 2048.0f);

    float ssc = 0.f;
#pragma unroll
    for (int i = 0; i < 8; ++i) { float d = vv[i] - mu; ssc += d * d; }
#pragma unroll
    for (int off = 32; off > 0; off >>= 1) ssc += __shfl_down(ssc, off);
    __syncthreads();
    if (lane == 0) rS[wid] = ssc;
    __syncthreads();
    ssc = rS[0] + rS[1] + rS[2] + rS[3];

    const float var  = ssc * (1.0f / 2048.0f);
    const float rstd = 1.0f / sqrtf(var + 1e-5f);
    float am = fmaxf(mx - mu, mu - mn) * rstd;
    am = fmaxf(am, 1e-5f);
    const float scale = 127.0f / am;

    unsigned int b0 = 0, b1 = 0;
#pragma unroll
    for (int i = 0; i < 8; ++i) {
        float xn = (vv[i] - mu) * rstd;
        int qi = (int)fminf(fmaxf(rintf(xn * scale), -128.0f), 127.0f);
        unsigned int byte = (unsigned int)(qi & 0xff);
        if (i < 4) b0 |= byte << (i * 8);
        else       b1 |= byte << ((i - 4) * 8);
    }
    int* orow = (int*)(xq + (long long)t * 2048);
    orow[tid]       = (int)b0;
    orow[tid + 256] = (int)b1;
    if (tid == 0) xinv[t] = am / 127.0f;
}

// ---------- LN + quant over h rows (d=8192, fp16 in, int8 out) ----------
__global__ __launch_bounds__(256) void ln_quant_h(
    const unsigned short* __restrict__ h, signed char* __restrict__ hq,
    float* __restrict__ hinv)
{
    const long long t = blockIdx.x;
    const int tid = threadIdx.x;
    const int lane = tid & 63, wid = tid >> 6;
    const unsigned short* row = h + t * 8192;

    uint4 raw[4];
    float v[32];
#pragma unroll
    for (int c = 0; c < 4; ++c) raw[c] = ((const uint4*)row)[c * 256 + tid];
#pragma unroll
    for (int c = 0; c < 4; ++c) {
        unsigned int u[4] = {raw[c].x, raw[c].y, raw[c].z, raw[c].w};
#pragma unroll
        for (int k = 0; k < 4; ++k) {
            f16x2 p = __builtin_bit_cast(f16x2, u[k]);
            v[c * 8 + k * 2 + 0] = (float)p[0];
            v[c * 8 + k * 2 + 1] = (float)p[1];
        }
    }

    float s = 0.f, mn = v[0], mx = v[0];
#pragma unroll
    for (int i = 0; i < 32; ++i) { s += v[i]; mn = fminf(mn, v[i]); mx = fmaxf(mx, v[i]); }
#pragma unroll
    for (int off = 32; off > 0; off >>= 1) {
        s += __shfl_down(s, off);
        mn = fminf(mn, __shfl_down(mn, off));
        mx = fmaxf(mx, __shfl_down(mx, off));
    }
    __shared__ float rS[4], rMn[4], rMx[4];
    if (lane == 0) { rS[wid] = s; rMn[wid] = mn; rMx[wid] = mx; }
    __syncthreads();
    s  = rS[0] + rS[1] + rS[2] + rS[3];
    mn = fminf(fminf(rMn[0], rMn[1]), fminf(rMn[2], rMn[3]));
    mx = fmaxf(fmaxf(rMx[0], rMx[1]), fmaxf(rMx[2], rMx[3]));
    const float mu = s * (1.0f / 8192.0f);

    float ssc = 0.f;
#pragma unroll
    for (int i = 0; i < 32; ++i) { float d = v[i] - mu; ssc += d * d; }
#pragma unroll
    for (int off = 32; off > 0; off >>= 1) ssc += __shfl_down(ssc, off);
    __syncthreads();
    if (lane == 0) rS[wid] = ssc;
    __syncthreads();
    ssc = rS[0] + rS[1] + rS[2] + rS[3];

    const float var  = ssc * (1.0f / 8192.0f);
    const float rstd = 1.0f / sqrtf(var + 1e-5f);
    float am = fmaxf(mx - mu, mu - mn) * rstd;
    am = fmaxf(am, 1e-5f);
    const float scale = 127.0f / am;

    signed char* orow = hq + t * 8192;
#pragma unroll
    for (int c = 0; c < 4; ++c) {
        unsigned int b0 = 0, b1 = 0;
#pragma unroll
        for (int k = 0; k < 8; ++k) {
            float xn = (v[c * 8 + k] - mu) * rstd;
            int qi = (int)fminf(fmaxf(rintf(xn * scale), -128.0f), 127.0f);
            unsigned int byte = (unsigned int)(qi & 0xff);
            if (k < 4) b0 |= byte << (k * 8);
            else       b1 |= byte << ((k - 4) * 8);
        }
        int2 o; o.x = (int)b0; o.y = (int)b1;
        ((int2*)orow)[c * 256 + tid] = o;
    }
    if (tid == 0) hinv[t] = am / 127.0f;
}

// ---------- deterministic |w| reduction (stage 1) ----------
__global__ __launch_bounds__(256) void reduce_abs(
    const float4* __restrict__ w4, int n4, float* __restrict__ partial)
{
    const int tid = threadIdx.x;
    const int lane = tid & 63, wid = tid >> 6;
    float s = 0.f;
    for (int i = blockIdx.x * 256 + tid; i < n4; i += gridDim.x * 256) {
        float4 v = w4[i];
        s += fabsf(v.x) + fabsf(v.y) + fabsf(v.z) + fabsf(v.w);
    }
#pragma unroll
    for (int off = 32; off > 0; off >>= 1) s += __shfl_down(s, off);
    __shared__ float rS[4];
    if (lane == 0) rS[wid] = s;
    __syncthreads();
    if (tid == 0) partial[blockIdx.x] = rS[0] + rS[1] + rS[2] + rS[3];
}

// ---------- stage 2: scales for both weights ----------
__global__ __launch_bounds__(256) void finalize_scales(
    const float* __restrict__ p1, const float* __restrict__ p2,
    float* __restrict__ scales)
{
    const int tid = threadIdx.x;
    const int lane = tid & 63, wid = tid >> 6;
    float s1 = 0.f, s2 = 0.f;
    for (int i = tid; i < 1024; i += 256) { s1 += p1[i]; s2 += p2[i]; }
#pragma unroll
    for (int off = 32; off > 0; off >>= 1) {
        s1 += __shfl_down(s1, off);
        s2 += __shfl_down(s2, off);
    }
    __shared__ float rA[4], rB[4];
    if (lane == 0) { rA[wid] = s1; rB[wid] = s2; }
    __syncthreads();
    if (tid == 0) {
        float m1 = fmaxf((rA[0] + rA[1] + rA[2] + rA[3]) * (1.0f / 16777216.0f), 1e-8f);
        float m2 = fmaxf((rB[0] + rB[1] + rB[2] + rB[3]) * (1.0f / 16777216.0f), 1e-8f);
        scales[0] = m1;
        scales[1] = m2;
    }
}

// ---------- ternary weight quant: int8 codes in {-1,0,+1} ----------
__global__ __launch_bounds__(256) void quant_w(
    const float4* __restrict__ w4, signed char* __restrict__ wq,
    const float* __restrict__ scales, int sidx, int n4)
{
    const float s = scales[sidx];
    for (int i = blockIdx.x * 256 + threadIdx.x; i < n4; i += gridDim.x * 256) {
        float4 v = w4[i];
        int q0 = (int)fminf(fmaxf(rintf(v.x / s), -1.0f), 1.0f);
        int q1 = (int)fminf(fmaxf(rintf(v.y / s), -1.0f), 1.0f);
        int q2 = (int)fminf(fmaxf(rintf(v.z / s), -1.0f), 1.0f);
        int q3 = (int)fminf(fmaxf(rintf(v.w / s), -1.0f), 1.0f);
        unsigned int p = (unsigned int)(q0 & 0xff) | ((unsigned int)(q1 & 0xff) << 8)
                       | ((unsigned int)(q2 & 0xff) << 16) | ((unsigned int)(q3 & 0xff) << 24);
        ((unsigned int*)wq)[i] = p;
    }
}

// ---------- launch ----------
extern "C" void kernel_launch(void* const* d_in, const int* in_sizes, int n_in,
                              void* d_out, int out_size, void* d_ws, size_t ws_size,
                              hipStream_t stream)
{
    const float* x  = (const float*)d_in[0];   // 8192 x 2048
    const float* w1 = (const float*)d_in[1];   // 8192 x 2048
    const float* b1 = (const float*)d_in[2];   // 8192
    const float* w2 = (const float*)d_in[3];   // 2048 x 8192
    const float* b2 = (const float*)d_in[4];   // 2048
    float* out = (float*)d_out;                // 8192 x 2048

    char* ws = (char*)d_ws;
    const size_t SZ_WQ = 16777216;             // 8192*2048 int8
    signed char* w1q = (signed char*)(ws);
    signed char* w2q = (signed char*)(ws + SZ_WQ);
    signed char* xq  = (signed char*)(ws + 2 * SZ_WQ);
    unsigned short* h = (unsigned short*)(ws + 3 * SZ_WQ);          // fp16, 128 MB
    signed char* hq  = (signed char*)(ws + 3 * SZ_WQ + 134217728);  // int8, 64 MB
    float* xinv   = (float*)(ws + 3 * SZ_WQ + 134217728 + 67108864);
    float* hinv   = xinv + 8192;
    float* part1  = hinv + 8192;
    float* part2  = part1 + 1024;
    float* scales = part2 + 1024;

    const int N4W = 4194304;  // 16.7M / 4

    reduce_abs<<<1024, 256, 0, stream>>>((const float4*)w1, N4W, part1);
    reduce_abs<<<1024, 256, 0, stream>>>((const float4*)w2, N4W, part2);
    finalize_scales<<<1, 256, 0, stream>>>(part1, part2, scales);
    quant_w<<<4096, 256, 0, stream>>>((const float4*)w1, w1q, scales, 0, N4W);
    quant_w<<<4096, 256, 0, stream>>>((const float4*)w2, w2q, scales, 1, N4W);
    ln_quant_x<<<8192, 256, 0, stream>>>(x, xq, xinv);

    // h = gelu(xq @ w1q^T * (sw1*xinv) + b1), stored fp16
    gemm_i8_8ph<true, _Float16><<<dim3(32, 32), 512, 0, stream>>>(
        xq, w1q, xinv, &scales[0], b1, (_Float16*)h, 8192, 8192, 2048);

    ln_quant_h<<<8192, 256, 0, stream>>>(h, hq, hinv);

    // out = hq @ w2q^T * (sw2*hinv) + b2, fp32
    gemm_i8_8ph<false, float><<<dim3(8, 32), 512, 0, stream>>>(
        hq, w2q, hinv, &scales[1], b2, out, 8192, 2048, 8192);
}